// Round 1
// baseline (746.406 us; speedup 1.0000x reference)
//
#include <hip/hip_runtime.h>
#include <cmath>

#define BB 256
#define TT 512
#define NN 128

__device__ __forceinline__ float wave_max64(float v) {
    #pragma unroll
    for (int off = 32; off; off >>= 1) v = fmaxf(v, __shfl_xor(v, off));
    return v;
}
__device__ __forceinline__ float wave_sum64(float v) {
    #pragma unroll
    for (int off = 32; off; off >>= 1) v += __shfl_xor(v, off);
    return v;
}
// argmax over 128 values held as (v0 at index 2l, v1 at index 2l+1) across 64 lanes.
// First-index tie-break (matches np.argmax). Max via fmax tree is exact, so the
// winning value equals one of the inputs bitwise.
__device__ __forceinline__ int wave_argmax128(float v0, float v1, int l) {
    float m = fmaxf(v0, v1);
    float wm = wave_max64(m);
    unsigned long long ball = __ballot(m == wm);
    int lane = __ffsll((unsigned long long)ball) - 1;
    int idx = (v0 == wm) ? (2 * l) : (2 * l + 1);
    return __shfl(idx, lane);
}

// Forward: fused Viterbi (max-plus, bitwise-exact fp32) + log-norm
// (linear domain with power-of-2 renorm). One block per batch, 256 threads:
// j = tid&127 (output column), h = tid>>7 (half of the i-reduction).
__global__ __launch_bounds__(256, 1) void fwd_kernel(
        const float* __restrict__ em, const int* __restrict__ mask,
        const float* __restrict__ trans, float* __restrict__ ahist,
        float* __restrict__ lognorm) {
    const int b = blockIdx.x;
    const int tid = threadIdx.x;
    const int j = tid & 127;
    const int h = tid >> 7;

    // Register-cache trans column halves: TR[k] = trans[64h+k][j], E = exp(TR).
    float TR[64], E[64];
    const float* tcol = trans + (size_t)(h * 64) * NN + j;
    #pragma unroll
    for (int k = 0; k < 64; ++k) TR[k] = tcol[(size_t)k * NN];
    #pragma unroll
    for (int k = 0; k < 64; ++k) E[k] = __expf(TR[k]);

    __shared__ __align__(16) float s_sh[NN];   // linear-domain lognorm alpha
    __shared__ __align__(16) float av_sh[NN];  // viterbi alpha (exact fp32)
    __shared__ float pd[NN], pm[NN];           // partials from h==1
    __shared__ int mask_sh[TT];
    __shared__ int k_sh;
    __shared__ int kacc_sh;

    mask_sh[tid] = mask[b * TT + tid];
    mask_sh[tid + 256] = mask[b * TT + 256 + tid];
    if (tid == 0) kacc_sh = 0;

    const float* emb = em + (size_t)b * TT * NN;
    float* ah = ahist + (size_t)b * TT * NN;
    if (h == 0) {
        float a0 = emb[j];
        av_sh[j] = a0;
        s_sh[j] = __expf(a0);   // |a0| <= ~6 -> no overflow before first renorm
        ah[j] = a0;             // alpha history t=0
    }
    float e_next = (h == 0) ? emb[NN + j] : 0.0f;
    __syncthreads();

    for (int t = 1; t < TT; ++t) {
        float e_cur = e_next;
        if (h == 0 && t + 1 < TT) e_next = emb[(size_t)(t + 1) * NN + j];
        const int m = mask_sh[t];

        const float* sb = s_sh + h * 64;
        const float* ab = av_sh + h * 64;
        float d0 = 0.f, d1 = 0.f, d2 = 0.f, d3 = 0.f;
        float m0 = -INFINITY, m1 = -INFINITY, m2 = -INFINITY, m3 = -INFINITY;
        #pragma unroll
        for (int q = 0; q < 16; ++q) {
            float4 sv = *(const float4*)(sb + 4 * q);
            float4 av = *(const float4*)(ab + 4 * q);
            d0 = fmaf(sv.x, E[4 * q + 0], d0);
            m0 = fmaxf(m0, av.x + TR[4 * q + 0]);   // plain add: bitwise == reference
            d1 = fmaf(sv.y, E[4 * q + 1], d1);
            m1 = fmaxf(m1, av.y + TR[4 * q + 1]);
            d2 = fmaf(sv.z, E[4 * q + 2], d2);
            m2 = fmaxf(m2, av.z + TR[4 * q + 2]);
            d3 = fmaf(sv.w, E[4 * q + 3], d3);
            m3 = fmaxf(m3, av.w + TR[4 * q + 3]);
        }
        float dot = (d0 + d1) + (d2 + d3);
        float best = fmaxf(fmaxf(m0, m1), fmaxf(m2, m3));

        if (h == 1) { pd[j] = dot; pm[j] = best; }
        __syncthreads();
        if (h == 0) {
            dot += pd[j];
            best = fmaxf(best, pm[j]);
            float av_new, s_new;
            if (m) {
                av_new = best + e_cur;
                s_new = dot * __expf(e_cur);
            } else {
                av_new = av_sh[j];
                s_new = s_sh[j];
            }
            av_sh[j] = av_new;
            s_sh[j] = s_new;
            ah[(size_t)t * NN + j] = av_new;
        }
        __syncthreads();

        if ((t & 3) == 3) {  // renorm s every 4 steps: scale by exact power of 2
            if (tid < 64) {
                float v = fmaxf(s_sh[2 * tid], s_sh[2 * tid + 1]);
                v = wave_max64(v);
                if (tid == 0) {
                    int kk = (v > 0.f) ? ilogbf(v) : 0;
                    k_sh = kk;
                    kacc_sh += kk;
                }
            }
            __syncthreads();
            int kk = k_sh;
            if (h == 0) s_sh[j] = ldexpf(s_sh[j], -kk);
            __syncthreads();
        }
    }

    if (tid < 64) {
        float v = s_sh[2 * tid] + s_sh[2 * tid + 1];
        v = wave_sum64(v);
        if (tid == 0) lognorm[b] = logf(v) + (float)kacc_sh * 0.6931471805599453f;
    }
}

// Backward: recompute argmax from exact stored alphas. One wave per batch.
__global__ __launch_bounds__(64, 1) void bwd_kernel(
        const float* __restrict__ ahist, const int* __restrict__ mask,
        const float* __restrict__ trans, float* __restrict__ outp) {
    const int b = blockIdx.x;
    const int l = threadIdx.x;

    // Stage trans transposed, stride 129 (pad) for conflict-free column reads.
    __shared__ float Tt[NN * 129];
    #pragma unroll 4
    for (int it = 0; it < 256; ++it) {
        int idx = it * 64 + l;
        int i = idx >> 7;
        int jj = idx & 127;
        Tt[jj * 129 + i] = trans[idx];
    }

    const float* ah = ahist + (size_t)b * TT * NN;
    float* op = outp + (size_t)b * TT;
    __syncthreads();

    float v0 = ah[(size_t)(TT - 1) * NN + 2 * l];
    float v1 = ah[(size_t)(TT - 1) * NN + 2 * l + 1];
    int tag = wave_argmax128(v0, v1, l);
    if (l == 0) op[TT - 1] = (float)tag;

    float a0 = ah[(size_t)(TT - 2) * NN + 2 * l];
    float a1 = ah[(size_t)(TT - 2) * NN + 2 * l + 1];
    for (int t = TT - 1; t >= 1; --t) {
        float c0 = a0, c1 = a1;
        if (t >= 2) {
            a0 = ah[(size_t)(t - 2) * NN + 2 * l];
            a1 = ah[(size_t)(t - 2) * NN + 2 * l + 1];
        }
        int m = mask[b * TT + t];
        if (m) {
            float w0 = c0 + Tt[tag * 129 + 2 * l];
            float w1 = c1 + Tt[tag * 129 + 2 * l + 1];
            tag = wave_argmax128(w0, w1, l);
        }
        if (l == 0) op[t - 1] = (float)tag;
    }
}

// Gold-path score + final LL. One block (128 threads) per batch.
__global__ __launch_bounds__(128, 1) void score_kernel(
        const float* __restrict__ em, const int* __restrict__ tags,
        const int* __restrict__ mask, const float* __restrict__ trans,
        const float* __restrict__ lognorm, float* __restrict__ out_ll) {
    const int b = blockIdx.x;
    const int tid = threadIdx.x;
    float acc = 0.f;
    for (int t = tid; t < TT; t += 128) {
        int tg = tags[b * TT + t];
        float mf = (float)mask[b * TT + t];
        acc += em[((size_t)b * TT + t) * NN + tg] * mf;
        if (t >= 1) {
            int tp = tags[b * TT + t - 1];
            acc += trans[tp * NN + tg] * mf;
        }
    }
    acc = wave_sum64(acc);
    __shared__ float rs[2];
    if ((tid & 63) == 0) rs[tid >> 6] = acc;
    __syncthreads();
    if (tid == 0) out_ll[b] = (rs[0] + rs[1]) - lognorm[b];
}

__global__ void copy_trans_kernel(const float* __restrict__ trans,
                                  float* __restrict__ dst) {
    int i = blockIdx.x * 256 + threadIdx.x;
    if (i < NN * NN) dst[i] = trans[i];
}

extern "C" void kernel_launch(void* const* d_in, const int* in_sizes, int n_in,
                              void* d_out, int out_size, void* d_ws, size_t ws_size,
                              hipStream_t stream) {
    const float* em = (const float*)d_in[0];
    const int* tags = (const int*)d_in[1];
    const int* mask = (const int*)d_in[2];
    const float* trans = (const float*)d_in[3];

    float* out = (float*)d_out;
    float* out_ll = out;                       // [256]
    float* out_trans = out + BB;               // [128*128]
    float* out_pred = out + BB + NN * NN;      // [256*512] tags as float

    float* ahist = (float*)d_ws;                         // B*T*N fp32 = 64 MB
    float* lognorm = ahist + (size_t)BB * TT * NN;       // [256]

    hipLaunchKernelGGL(fwd_kernel, dim3(BB), dim3(256), 0, stream,
                       em, mask, trans, ahist, lognorm);
    hipLaunchKernelGGL(copy_trans_kernel, dim3(64), dim3(256), 0, stream,
                       trans, out_trans);
    hipLaunchKernelGGL(score_kernel, dim3(BB), dim3(128), 0, stream,
                       em, tags, mask, trans, lognorm, out_ll);
    hipLaunchKernelGGL(bwd_kernel, dim3(BB), dim3(64), 0, stream,
                       ahist, mask, trans, out_pred);
}